// Round 8
// baseline (179.616 us; speedup 1.0000x reference)
//
#include <hip/hip_runtime.h>
#include <hip/hip_fp16.h>

// Problem constants (fixed by the reference)
#define NG    4096        // graphs
#define NPG   198         // nodes per graph
#define EPG   1584        // edges per graph
#define ETOT  (NG * EPG)  // total edges
#define SH    24          // halves per LDS feature row (48 B)

#define BC2(u) __builtin_bit_cast(__half2, (u))

typedef _Float16 f16x4 __attribute__((ext_vector_type(4)));
typedef float    f32x4 __attribute__((ext_vector_type(4)));

// Workspace layout (f16 units):
//   H    [NG][396] f16
//   WTB  (MLP weights, B-fragment layout)   114688 f16
//   CB   (conv weights, B-fragment layout)    3584 f16
#define H_F16S    (NG * 396)
#define WTB1_OFF  83200
#define WTB2_OFF  106496
#define WTB3_OFF  113664
#define WTB_TOTAL 114688
#define CB_TOTAL  3584

// ---------------------------------------------------------------------------
// MLP weight pack: WTB[kc][n][ki] = (f16)W[n][kc*16+ki], zero-padded.
// ---------------------------------------------------------------------------
__global__ __launch_bounds__(256) void wtrans16_kernel(
    const float* __restrict__ w0, const float* __restrict__ w1,
    const float* __restrict__ w2, const float* __restrict__ w3,
    _Float16* __restrict__ wtb)
{
    const int idx = blockIdx.x * 256 + threadIdx.x;
    if (idx >= WTB_TOTAL) return;
    const float* w; int K, N, NPAD, rel;
    if (idx < 83200)       { w = w0; K = 396; N = 200; NPAD = 208; rel = idx; }
    else if (idx < 106496) { w = w1; K = 200; N = 100; NPAD = 112; rel = idx - 83200; }
    else if (idx < 113664) { w = w2; K = 100; N = 50;  NPAD = 64;  rel = idx - 106496; }
    else                   { w = w3; K = 50;  N = 10;  NPAD = 16;  rel = idx - 113664; }
    const int span = NPAD * 16;
    const int kc = rel / span;
    const int r  = rel - kc * span;
    const int n  = r >> 4, ki = r & 15;
    const int k  = kc * 16 + ki;
    const float v = (n < N && k < K) ? w[n * K + k] : 0.f;
    wtb[idx] = (_Float16)v;
}

// ---------------------------------------------------------------------------
// Conv weight pack: per layer, rel + root matrices in B-fragment layout
//   CB block: [kc][n (NT*16)][ki (16)], zero-padded in K and N.
// Offsets: L0 rel@0 root@512 | L1 rel@1024 root@1536 | L2 rel@2048 root@2304
//          L3 rel@2560 root@2816 | L4 rel@3072 root@3328
// ---------------------------------------------------------------------------
__global__ __launch_bounds__(256) void wconv16_kernel(
    const float* wr0, const float* wq0, const float* wr1, const float* wq1,
    const float* wr2, const float* wq2, const float* wr3, const float* wq3,
    const float* wr4, const float* wq4, _Float16* __restrict__ cb)
{
    const int idx = blockIdx.x * 256 + threadIdx.x;
    if (idx >= CB_TOTAL) return;
    const float* w; int CIN, COUT, NT, q;
    if (idx < 1024)      { CIN = 2;  COUT = 20; NT = 2; int r = idx;        int h = r >= 512; q = r - h * 512; w = h ? wq0 : wr0; }
    else if (idx < 2048) { CIN = 20; COUT = 15; NT = 1; int r = idx - 1024; int h = r >= 512; q = r - h * 512; w = h ? wq1 : wr1; }
    else if (idx < 2560) { CIN = 15; COUT = 10; NT = 1; int r = idx - 2048; int h = r >= 256; q = r - h * 256; w = h ? wq2 : wr2; }
    else if (idx < 3072) { CIN = 10; COUT = 5;  NT = 1; int r = idx - 2560; int h = r >= 256; q = r - h * 256; w = h ? wq3 : wr3; }
    else                 { CIN = 5;  COUT = 2;  NT = 1; int r = idx - 3072; int h = r >= 256; q = r - h * 256; w = h ? wq4 : wr4; }
    const int chunk = NT * 256;
    const int kc = q / chunk, r2 = q - kc * chunk;
    const int n = r2 >> 4, ki = r2 & 15, k = kc * 16 + ki;
    const float v = (n < COUT && k < CIN) ? w[n * CIN + k] : 0.f;
    cb[idx] = (_Float16)v;
}

// ---------------------------------------------------------------------------
// Conv gather: node-per-thread, f32 accumulation (f16 row data, f32 weight).
// Writes agg row to bufAgg in f16, zero-padded to SH halves.
// ---------------------------------------------------------------------------
template <int CIN>
__device__ __forceinline__ void conv_gather(
    const _Float16* __restrict__ bufIn, _Float16* __restrict__ bufAgg,
    const unsigned short* __restrict__ s_src, const float* __restrict__ s_ewf,
    const unsigned* __restrict__ row_start, const unsigned* __restrict__ perm,
    int tid)
{
    if (tid >= NPG) return;
    const int node = (int)perm[tid];
    constexpr int MS = (CIN + 1) / 2;
    constexpr int NW = ((MS + 3) / 4) * 4;   // words read (within 12-word row)

    float acc[CIN];
#pragma unroll
    for (int c = 0; c < CIN; ++c) acc[c] = 0.f;

    const unsigned jb = row_start[node], je = row_start[node + 1];
    for (unsigned j = jb; j < je; ++j) {
        const int   src = (int)s_src[j];
        const float w   = s_ewf[j];
        const unsigned* rw = (const unsigned*)(bufIn + src * SH);
        unsigned wv[NW];
        if constexpr (MS == 1) {
            wv[0] = rw[0];
        } else {
#pragma unroll
            for (int qn = 0; qn < NW / 4; ++qn) {
                const uint4 q = ((const uint4*)rw)[qn];
                wv[4*qn] = q.x; wv[4*qn+1] = q.y; wv[4*qn+2] = q.z; wv[4*qn+3] = q.w;
            }
        }
#pragma unroll
        for (int p = 0; p < MS; ++p) {
            const float2 f = __half22float2(BC2(wv[p]));
            acc[2*p] = fmaf(w, f.x, acc[2*p]);
            if (2*p + 1 < CIN) acc[2*p+1] = fmaf(w, f.y, acc[2*p+1]);
        }
    }

    unsigned ow[12];
#pragma unroll
    for (int p = 0; p < 12; ++p) {
        const float lo = (2*p     < CIN) ? acc[2*p]     : 0.f;
        const float hi = (2*p + 1 < CIN) ? acc[2*p + 1] : 0.f;
        ow[p] = __builtin_bit_cast(unsigned, __floats2half2_rn(lo, hi));
    }
    unsigned* orow = (unsigned*)(bufAgg + node * SH);
#pragma unroll
    for (int qn = 0; qn < 3; ++qn)
        ((uint4*)orow)[qn] = make_uint4(ow[4*qn], ow[4*qn+1], ow[4*qn+2], ow[4*qn+3]);
}

// ---------------------------------------------------------------------------
// Conv dense via MFMA: H' = ReLU(AGG @ Wrel^T + H @ Wroot^T + b).
// Fragment layouts identical to the validated MLP kernel.
// ---------------------------------------------------------------------------
template <int CIN, int COUT, int KCA, int NT>
__device__ __forceinline__ void conv_dense(
    const _Float16* __restrict__ bufIn,  // H (root operand), stride SH
    const _Float16* __restrict__ bufAgg, // AGG, stride SH
    _Float16* __restrict__ bufOut,       // H', stride SH
    const _Float16* __restrict__ wbrel, const _Float16* __restrict__ wbroot,
    const float* __restrict__ bias, int tid)
{
    const int lane = tid & 63, wid = tid >> 6;
    const int lrow = lane & 15, lgrp = lane >> 4;

    for (int p = wid; p < 13 * NT; p += 4) {
        const int mt = p / NT, nt = p - mt * NT;
        const int arow = mt * 16 + lrow;
        const _Float16* aA = bufAgg + arow * SH + lgrp * 4;
        const _Float16* aH = bufIn  + arow * SH + lgrp * 4;
        const int n = nt * 16 + lrow;
        const _Float16* bR = wbrel  + n * 16 + lgrp * 4;
        const _Float16* bT = wbroot + n * 16 + lgrp * 4;

        f32x4 acc = {0.f, 0.f, 0.f, 0.f};
#pragma unroll
        for (int kc = 0; kc < KCA; ++kc) {
            acc = __builtin_amdgcn_mfma_f32_16x16x16f16(
                *(const f16x4*)(aA + kc * 16),
                *(const f16x4*)(bR + kc * (NT * 256)), acc, 0, 0, 0);
            acc = __builtin_amdgcn_mfma_f32_16x16x16f16(
                *(const f16x4*)(aH + kc * 16),
                *(const f16x4*)(bT + kc * (NT * 256)), acc, 0, 0, 0);
        }
        if (n < COUT) {
            const float bv = bias[n];
#pragma unroll
            for (int j = 0; j < 4; ++j) {
                const int r = mt * 16 + lgrp * 4 + j;
                if (r < NPG)
                    bufOut[r * SH + n] = (_Float16)fmaxf(acc[j] + bv, 0.f);
            }
        }
    }
}

__global__ __launch_bounds__(256) void conv_kernel(
    const float* __restrict__ x,
    const int*   __restrict__ eidx,
    const float* __restrict__ ew,
    const float* __restrict__ br0, const float* __restrict__ br1,
    const float* __restrict__ br2, const float* __restrict__ br3,
    const float* __restrict__ br4,
    const _Float16* __restrict__ cb,     // packed conv weights
    _Float16* __restrict__ H)            // row-major [NG][396] f16
{
    __shared__ unsigned short s_src[EPG];                 // 3168 B
    __shared__ float          s_ewf[EPG];                 // 6336 B
    __shared__ unsigned cnt[256];
    __shared__ unsigned cursor[256];
    __shared__ unsigned row_start[NPG + 1];
    __shared__ unsigned wsum[4];
    __shared__ unsigned dhist[64];
    __shared__ unsigned dcur[64];
    __shared__ unsigned perm[NPG];
    __shared__ __align__(16) _Float16 bufA[208 * SH + 32];   // 5056 B
    __shared__ __align__(16) _Float16 bufB[208 * SH + 32];
    __shared__ __align__(16) _Float16 bufG[208 * SH + 32];   // AGG

    const int g = blockIdx.x, tid = threadIdx.x;
    const int ebase = g * EPG, nbase = g * NPG;
    const int lane = tid & 63, wid = tid >> 6;

    // --- zero feature buffers (NaN-safety for padded/garbage lanes) ---------
    {
        unsigned* zA = (unsigned*)bufA;
        unsigned* zB = (unsigned*)bufB;
        unsigned* zG = (unsigned*)bufG;
        for (int i = tid; i < (208 * SH + 32) / 2; i += 256) {
            zA[i] = 0u; zB[i] = 0u; zG[i] = 0u;
        }
    }

    // --- load all edges once into registers ---------------------------------
    const int4*   s4 = (const int4*)(eidx + ebase);
    const int4*   d4 = (const int4*)(eidx + ETOT + ebase);
    const float4* w4 = (const float4*)(ew + ebase);
    const int4   sa = s4[tid];
    const int4   da = d4[tid];
    const float4 wa = w4[tid];
    const bool hasb = tid < (EPG / 4 - 256);
    int4 sb = {0,0,0,0}, db = {0,0,0,0}; float4 wb = {0,0,0,0};
    if (hasb) { sb = s4[tid + 256]; db = d4[tid + 256]; wb = w4[tid + 256]; }

    cnt[tid] = 0u;
    __syncthreads();
    atomicAdd(&cnt[da.x - nbase], 1u); atomicAdd(&cnt[da.y - nbase], 1u);
    atomicAdd(&cnt[da.z - nbase], 1u); atomicAdd(&cnt[da.w - nbase], 1u);
    if (hasb) {
        atomicAdd(&cnt[db.x - nbase], 1u); atomicAdd(&cnt[db.y - nbase], 1u);
        atomicAdd(&cnt[db.z - nbase], 1u); atomicAdd(&cnt[db.w - nbase], 1u);
    }
    __syncthreads();

    const unsigned v = cnt[tid];
    unsigned inc = v;
#pragma unroll
    for (int s = 1; s < 64; s <<= 1) {
        const unsigned t = (unsigned)__shfl_up((int)inc, s);
        if (lane >= s) inc += t;
    }
    if (lane == 63) wsum[wid] = inc;
    __syncthreads();
    unsigned pre = 0;
    for (int w = 0; w < wid; ++w) pre += wsum[w];
    const unsigned excl = pre + inc - v;
    if (tid <= NPG) row_start[tid] = excl;
    if (tid < NPG)  cursor[tid]    = excl;
    __syncthreads();

    {
        auto place = [&](int s, int d, float w) {
            const int dl = d - nbase;
            const unsigned slot = atomicAdd(&cursor[dl], 1u);
            s_src[slot] = (unsigned short)(s - nbase);
            s_ewf[slot] = w;
        };
        place(sa.x, da.x, wa.x); place(sa.y, da.y, wa.y);
        place(sa.z, da.z, wa.z); place(sa.w, da.w, wa.w);
        if (hasb) {
            place(sb.x, db.x, wb.x); place(sb.y, db.y, wb.y);
            place(sb.z, db.z, wb.z); place(sb.w, db.w, wb.w);
        }
    }

    // pack x into bufA rows (word 0; rest stays zero)
    if (tid < NPG) {
        const float2 xv = ((const float2*)x)[nbase + tid];
        *(unsigned*)(bufA + tid * SH) =
            __builtin_bit_cast(unsigned, __floats2half2_rn(xv.x, xv.y));
    }

    // --- degree-sorted permutation ------------------------------------------
    if (tid < 64) dhist[tid] = 0u;
    __syncthreads();
    unsigned mydeg = 0u;
    if (tid < NPG) {
        mydeg = cnt[tid]; if (mydeg > 63u) mydeg = 63u;
        atomicAdd(&dhist[mydeg], 1u);
    }
    __syncthreads();
    if (tid < 64) {
        const unsigned dv = dhist[tid];
        unsigned sc = dv;
#pragma unroll
        for (int s = 1; s < 64; s <<= 1) {
            const unsigned t = (unsigned)__shfl_up((int)sc, s);
            if (lane >= s) sc += t;
        }
        dcur[tid] = sc - dv;
    }
    __syncthreads();
    if (tid < NPG) {
        const unsigned pos = atomicAdd(&dcur[mydeg], 1u);
        perm[pos] = (unsigned)tid;
    }
    __syncthreads();

    // --- 5 layers: gather (VALU, f32 accum) -> dense (MFMA) -----------------
#define LAYER(CIN, COUT, KCA, NT, FIN, FOUT, RELOFF, ROOTOFF, BR)             \
    conv_gather<CIN>(FIN, bufG, s_src, s_ewf, row_start, perm, tid);          \
    __syncthreads();                                                          \
    conv_dense<CIN, COUT, KCA, NT>(FIN, bufG, FOUT, cb + RELOFF,              \
                                   cb + ROOTOFF, BR, tid);                    \
    __syncthreads();

    LAYER(2,  20, 1, 2, bufA, bufB, 0,    512,  br0)
    LAYER(20, 15, 2, 1, bufB, bufA, 1024, 1536, br1)
    LAYER(15, 10, 1, 1, bufA, bufB, 2048, 2304, br2)
    LAYER(10, 5,  1, 1, bufB, bufA, 2560, 2816, br3)
    LAYER(5,  2,  1, 1, bufA, bufB, 3072, 3328, br4)
#undef LAYER

    // row-major f16 store: H[g][396] (word = half2 of channels 0,1 per node)
    if (tid < NPG)
        ((unsigned*)H)[g * 198 + tid] = *(const unsigned*)(bufB + tid * SH);
}

// ---------------------------------------------------------------------------
// MLP as fused MFMA GEMM chain (validated round-7 version, unchanged).
// ---------------------------------------------------------------------------
__device__ __forceinline__ void zero_words(void* p, int nwords, int tid)
{
    unsigned* u = (unsigned*)p;
    for (int i = tid; i < nwords; i += 256) u[i] = 0u;
}

template<int KC, int NTT, int NOUT, int SIN, int SOUT>
__device__ __forceinline__ void mfma_layer(
    const _Float16* __restrict__ inb,
    _Float16* __restrict__ outb,
    const _Float16* __restrict__ wtb,
    const float* __restrict__ bias, int tid)
{
    constexpr int NPAD = NTT * 16;
    const int lane = tid & 63, wid = tid >> 6;
    const int lrow = lane & 15, lgrp = lane >> 4;
    const _Float16* aptr = inb + lrow * SIN + lgrp * 4;

    for (int nt0 = wid; nt0 < NTT; nt0 += 8) {
        const int  nt1  = nt0 + 4;
        const bool has2 = nt1 < NTT;
        f32x4 acc0 = {0.f, 0.f, 0.f, 0.f};
        f32x4 acc1 = {0.f, 0.f, 0.f, 0.f};
        const int n0 = nt0 * 16 + lrow;
        const int n1 = nt1 * 16 + lrow;
        const _Float16* b0 = wtb + n0 * 16 + lgrp * 4;
        const _Float16* b1 = wtb + n1 * 16 + lgrp * 4;
#pragma unroll 4
        for (int kc = 0; kc < KC; ++kc) {
            const f16x4 a   = *(const f16x4*)(aptr + kc * 16);
            const f16x4 vb0 = *(const f16x4*)(b0 + (size_t)kc * (NPAD * 16));
            acc0 = __builtin_amdgcn_mfma_f32_16x16x16f16(a, vb0, acc0, 0, 0, 0);
            if (has2) {
                const f16x4 vb1 = *(const f16x4*)(b1 + (size_t)kc * (NPAD * 16));
                acc1 = __builtin_amdgcn_mfma_f32_16x16x16f16(a, vb1, acc1, 0, 0, 0);
            }
        }
        if (n0 < NOUT) {
            const float bv = bias[n0];
#pragma unroll
            for (int j = 0; j < 4; ++j)
                outb[(lgrp * 4 + j) * SOUT + n0] =
                    (_Float16)fmaxf(acc0[j] + bv, 0.f);
        }
        if (has2 && n1 < NOUT) {
            const float bv = bias[n1];
#pragma unroll
            for (int j = 0; j < 4; ++j)
                outb[(lgrp * 4 + j) * SOUT + n1] =
                    (_Float16)fmaxf(acc1[j] + bv, 0.f);
        }
    }
}

__global__ __launch_bounds__(256) void mlp_mfma_kernel(
    const _Float16* __restrict__ H,
    const _Float16* __restrict__ wtb,
    const float* __restrict__ lb0, const float* __restrict__ lb1,
    const float* __restrict__ lb2, const float* __restrict__ lb3,
    const float* __restrict__ lw4, const float* __restrict__ lb4,
    float* __restrict__ out)
{
    __shared__ __align__(16) _Float16 bufH[16 * 400];
    __shared__ __align__(16) _Float16 bufX[16 * 224];
    __shared__ __align__(16) _Float16 bufY[16 * 128];

    const int tid   = threadIdx.x;
    const int gbase = blockIdx.x * 16;

    {
        const unsigned* Hw = (const unsigned*)H + (size_t)gbase * 198;
        unsigned* bH = (unsigned*)bufH;
        for (int t = tid; t < 16 * 200; t += 256) {
            const int gg = t / 200, w = t - gg * 200;
            bH[gg * 200 + w] = (w < 198) ? Hw[gg * 198 + w] : 0u;
        }
        zero_words(bufX, 16 * 224 / 2, tid);
        zero_words(bufY, 16 * 128 / 2, tid);
    }
    __syncthreads();

    mfma_layer<25, 13, 200, 400, 224>(bufH, bufX, wtb, lb0, tid);
    __syncthreads();

    zero_words(bufH, 512, tid);
    mfma_layer<13, 7, 100, 224, 128>(bufX, bufY, wtb + WTB1_OFF, lb1, tid);
    __syncthreads();

    zero_words(bufX, 128, tid);
    mfma_layer<7, 4, 50, 128, 64>(bufY, bufH, wtb + WTB2_OFF, lb2, tid);
    __syncthreads();

    mfma_layer<4, 1, 10, 64, 16>(bufH, bufX, wtb + WTB3_OFF, lb3, tid);
    __syncthreads();

    if (tid < 16) {
        float l0 = lb4[0], l1 = lb4[1];
#pragma unroll
        for (int k = 0; k < 10; ++k) {
            const float hv = (float)bufX[tid * 16 + k];
            l0 = fmaf(hv, lw4[k],      l0);
            l1 = fmaf(hv, lw4[10 + k], l1);
        }
        const float m  = fmaxf(l0, l1);
        const float e0 = __expf(l0 - m), e1 = __expf(l1 - m);
        const float inv = 1.f / (e0 + e1);
        float2 p; p.x = e0 * inv; p.y = e1 * inv;
        ((float2*)out)[gbase + tid] = p;
    }
}

extern "C" void kernel_launch(void* const* d_in, const int* in_sizes, int n_in,
                              void* d_out, int out_size, void* d_ws, size_t ws_size,
                              hipStream_t stream)
{
    const float* x    = (const float*)d_in[0];
    const int*   eidx = (const int*)  d_in[1];
    const float* ew   = (const float*)d_in[2];

    const float* wr[5]; const float* br[5]; const float* wq[5];
    for (int i = 0; i < 5; ++i) {
        wr[i] = (const float*)d_in[3 + 3 * i];
        br[i] = (const float*)d_in[4 + 3 * i];
        wq[i] = (const float*)d_in[5 + 3 * i];
    }
    const float* lw[5]; const float* lb[5];
    for (int i = 0; i < 5; ++i) {
        lw[i] = (const float*)d_in[18 + 2 * i];
        lb[i] = (const float*)d_in[19 + 2 * i];
    }

    _Float16* wsH = (_Float16*)d_ws;                  // H: [NG][396] f16
    _Float16* wtb = wsH + (size_t)H_F16S;             // packed MLP weights
    _Float16* cb  = wtb + (size_t)WTB_TOTAL;          // packed conv weights

    wtrans16_kernel<<<(WTB_TOTAL + 255) / 256, 256, 0, stream>>>(
        lw[0], lw[1], lw[2], lw[3], wtb);

    wconv16_kernel<<<(CB_TOTAL + 255) / 256, 256, 0, stream>>>(
        wr[0], wq[0], wr[1], wq[1], wr[2], wq[2], wr[3], wq[3], wr[4], wq[4],
        cb);

    conv_kernel<<<NG, 256, 0, stream>>>(
        x, eidx, ew,
        br[0], br[1], br[2], br[3], br[4],
        cb, wsH);

    mlp_mfma_kernel<<<NG / 16, 256, 0, stream>>>(
        wsH, wtb,
        lb[0], lb[1], lb[2], lb[3],
        lw[4], lb[4],
        (float*)d_out);
}

// Round 10
// 123.287 us; speedup vs baseline: 1.4569x; 1.4569x over previous
//
#include <hip/hip_runtime.h>
#include <hip/hip_fp16.h>

// Problem constants (fixed by the reference)
#define NG    4096        // graphs
#define NPG   198         // nodes per graph
#define EPG   1584        // edges per graph
#define ETOT  (NG * EPG)  // total edges
#define SHW   12          // feature row stride in words (24 halves, 48 B)
#define NROW  208         // padded rows (13 m-tiles * 16)

#define BC2(u) __builtin_bit_cast(__half2, (u))

typedef _Float16 f16x4 __attribute__((ext_vector_type(4)));
typedef float    f32x4 __attribute__((ext_vector_type(4)));

// Workspace layout (f16 units):
#define H_F16S    (NG * 396)
#define WTB1_OFF  83200
#define WTB2_OFF  106496
#define WTB3_OFF  113664
#define WTB_TOTAL 114688
#define CB_TOTAL  3584

// ---------------------------------------------------------------------------
// MLP weight pack: WTB[kc][n][ki] = (f16)W[n][kc*16+ki], zero-padded.
// ---------------------------------------------------------------------------
__global__ __launch_bounds__(256) void wtrans16_kernel(
    const float* __restrict__ w0, const float* __restrict__ w1,
    const float* __restrict__ w2, const float* __restrict__ w3,
    _Float16* __restrict__ wtb)
{
    const int idx = blockIdx.x * 256 + threadIdx.x;
    if (idx >= WTB_TOTAL) return;
    const float* w; int K, N, NPAD, rel;
    if (idx < 83200)       { w = w0; K = 396; N = 200; NPAD = 208; rel = idx; }
    else if (idx < 106496) { w = w1; K = 200; N = 100; NPAD = 112; rel = idx - 83200; }
    else if (idx < 113664) { w = w2; K = 100; N = 50;  NPAD = 64;  rel = idx - 106496; }
    else                   { w = w3; K = 50;  N = 10;  NPAD = 16;  rel = idx - 113664; }
    const int span = NPAD * 16;
    const int kc = rel / span;
    const int r  = rel - kc * span;
    const int n  = r >> 4, ki = r & 15;
    const int k  = kc * 16 + ki;
    const float v = (n < N && k < K) ? w[n * K + k] : 0.f;
    wtb[idx] = (_Float16)v;
}

// ---------------------------------------------------------------------------
// Conv weight pack (B-fragment layout, zero-padded in K and N).
// Offsets: L1 rel@1024 root@1536 | L2 rel@2048 root@2304 | L3 rel@2560 root@2816
// ---------------------------------------------------------------------------
__global__ __launch_bounds__(256) void wconv16_kernel(
    const float* wr0, const float* wq0, const float* wr1, const float* wq1,
    const float* wr2, const float* wq2, const float* wr3, const float* wq3,
    const float* wr4, const float* wq4, _Float16* __restrict__ cb)
{
    const int idx = blockIdx.x * 256 + threadIdx.x;
    if (idx >= CB_TOTAL) return;
    const float* w; int CIN, COUT, NT, q;
    if (idx < 1024)      { CIN = 2;  COUT = 20; NT = 2; int r = idx;        int h = r >= 512; q = r - h * 512; w = h ? wq0 : wr0; }
    else if (idx < 2048) { CIN = 20; COUT = 15; NT = 1; int r = idx - 1024; int h = r >= 512; q = r - h * 512; w = h ? wq1 : wr1; }
    else if (idx < 2560) { CIN = 15; COUT = 10; NT = 1; int r = idx - 2048; int h = r >= 256; q = r - h * 256; w = h ? wq2 : wr2; }
    else if (idx < 3072) { CIN = 10; COUT = 5;  NT = 1; int r = idx - 2560; int h = r >= 256; q = r - h * 256; w = h ? wq3 : wr3; }
    else                 { CIN = 5;  COUT = 2;  NT = 1; int r = idx - 3072; int h = r >= 256; q = r - h * 256; w = h ? wq4 : wr4; }
    const int chunk = NT * 256;
    const int kc = q / chunk, r2 = q - kc * chunk;
    const int n = r2 >> 4, ki = r2 & 15, k = kc * 16 + ki;
    const float v = (n < COUT && k < CIN) ? w[n * CIN + k] : 0.f;
    cb[idx] = (_Float16)v;
}

// ---------------------------------------------------------------------------
// In-register conv layer (L0, L4): f32-accum gather (v_fma_mix) + f32 dense.
// f32 accumulation makes the atomic-placement edge order harmless (~1e-7
// reassociation noise instead of f16's ~1e-3) -> deterministic-enough output.
// ---------------------------------------------------------------------------
template <int CIN, int COUT, int SIN, int SOUT>
__device__ __forceinline__ void conv_layer_h(
    const unsigned* __restrict__ h_in,   // rows stride SIN (half2 words)
    unsigned* __restrict__ h_out,        // rows stride SOUT
    const unsigned* __restrict__ s_edge, // (f16w<<16)|src, sorted by dst
    const unsigned short* __restrict__ row_start,
    const unsigned short* __restrict__ perm,
    const float* __restrict__ wrel, const float* __restrict__ brel,
    const float* __restrict__ wroot, int tid)
{
    if (tid >= NPG) return;
    const int node = (int)perm[tid];
    constexpr int MS = (CIN + 1) / 2;

    float aggf[MS * 2];
#pragma unroll
    for (int c = 0; c < MS * 2; ++c) aggf[c] = 0.f;

    const unsigned jb = row_start[node], je = row_start[node + 1];
    for (unsigned j = jb; j < je; ++j) {
        const unsigned e  = s_edge[j];
        const float    wf = __half2float(__ushort_as_half((unsigned short)(e >> 16)));
        const unsigned* row = h_in + (e & 0xFFFFu) * SIN;
        unsigned wv[MS];
        if constexpr (SIN == 1) {
            wv[0] = row[0];
        } else {
            const uint4 q0 = *(const uint4*)row;
            wv[0] = q0.x;
            if constexpr (MS > 1) wv[1] = q0.y;
            if constexpr (MS > 2) wv[2] = q0.z;
            if constexpr (MS > 3) wv[3] = q0.w;
            if constexpr (MS > 4) {
                const uint4 q1 = *(const uint4*)(row + 4);
                wv[4] = q1.x;
                if constexpr (MS > 5) wv[5] = q1.y;
                if constexpr (MS > 6) wv[6] = q1.z;
                if constexpr (MS > 7) wv[7] = q1.w;
            }
            if constexpr (MS > 8) {
                const uint4 q2 = *(const uint4*)(row + 8);
                wv[8] = q2.x;
                if constexpr (MS > 9) wv[9] = q2.y;
            }
        }
#pragma unroll
        for (int p = 0; p < MS; ++p) {
            const __half2 h2 = BC2(wv[p]);
            aggf[2*p]     = fmaf(wf, __low2float(h2),  aggf[2*p]);
            aggf[2*p + 1] = fmaf(wf, __high2float(h2), aggf[2*p + 1]);
        }
    }

    float hv[MS * 2];
    {
        const unsigned* me = h_in + node * SIN;
#pragma unroll
        for (int p = 0; p < MS; ++p) {
            const __half2 h2 = BC2(me[p]);
            hv[2*p]     = __low2float(h2);
            hv[2*p + 1] = __high2float(h2);
        }
    }

    float outv[COUT];
#pragma unroll
    for (int o = 0; o < COUT; ++o) {
        float acc = brel[o];
#pragma unroll
        for (int c = 0; c < CIN; ++c) {
            acc = fmaf(aggf[c], wrel[o * CIN + c], acc);
            acc = fmaf(hv[c],   wroot[o * CIN + c], acc);
        }
        outv[o] = fmaxf(acc, 0.f);
    }

    if constexpr (SOUT == 1) {
        h_out[node] = __builtin_bit_cast(unsigned,
            __floats2half2_rn(outv[0], COUT > 1 ? outv[1] : 0.f));
    } else {
        unsigned ow[SOUT];
#pragma unroll
        for (int p = 0; p < SOUT; ++p) {
            const float lo = (2 * p     < COUT) ? outv[2 * p]     : 0.f;
            const float hi = (2 * p + 1 < COUT) ? outv[2 * p + 1] : 0.f;
            ow[p] = __builtin_bit_cast(unsigned, __floats2half2_rn(lo, hi));
        }
        unsigned* orow = h_out + node * SOUT;
#pragma unroll
        for (int qn = 0; qn < SOUT / 4; ++qn)
            *(uint4*)(orow + 4 * qn) =
                make_uint4(ow[4*qn], ow[4*qn+1], ow[4*qn+2], ow[4*qn+3]);
    }
}

// ---------------------------------------------------------------------------
// Gather-only (for MFMA layers): f32 accumulate (v_fma_mix), write f16 AGG.
// ---------------------------------------------------------------------------
template <int CIN>
__device__ __forceinline__ void gather_to_G(
    const unsigned* __restrict__ fin, unsigned* __restrict__ bufG,
    const unsigned* __restrict__ s_edge,
    const unsigned short* __restrict__ row_start,
    const unsigned short* __restrict__ perm, int tid)
{
    if (tid >= NPG) return;
    const int node = (int)perm[tid];
    constexpr int MS = (CIN + 1) / 2;

    float acc[MS * 2];
#pragma unroll
    for (int c = 0; c < MS * 2; ++c) acc[c] = 0.f;

    const unsigned jb = row_start[node], je = row_start[node + 1];
    for (unsigned j = jb; j < je; ++j) {
        const unsigned e  = s_edge[j];
        const float    wf = __half2float(__ushort_as_half((unsigned short)(e >> 16)));
        const unsigned* row = fin + (e & 0xFFFFu) * SHW;
        unsigned wv[MS];
        const uint4 q0 = *(const uint4*)row;
        wv[0] = q0.x;
        if constexpr (MS > 1) wv[1] = q0.y;
        if constexpr (MS > 2) wv[2] = q0.z;
        if constexpr (MS > 3) wv[3] = q0.w;
        if constexpr (MS > 4) {
            const uint4 q1 = *(const uint4*)(row + 4);
            wv[4] = q1.x;
            if constexpr (MS > 5) wv[5] = q1.y;
            if constexpr (MS > 6) wv[6] = q1.z;
            if constexpr (MS > 7) wv[7] = q1.w;
        }
        if constexpr (MS > 8) {
            const uint4 q2 = *(const uint4*)(row + 8);
            wv[8] = q2.x;
            if constexpr (MS > 9) wv[9] = q2.y;
        }
#pragma unroll
        for (int p = 0; p < MS; ++p) {
            const __half2 h2 = BC2(wv[p]);
            acc[2*p]     = fmaf(wf, __low2float(h2),  acc[2*p]);
            acc[2*p + 1] = fmaf(wf, __high2float(h2), acc[2*p + 1]);
        }
    }

    unsigned ow[SHW];
#pragma unroll
    for (int p = 0; p < SHW; ++p)
        ow[p] = (p < MS)
            ? __builtin_bit_cast(unsigned, __floats2half2_rn(acc[2*p], acc[2*p+1]))
            : 0u;
    unsigned* orow = bufG + node * SHW;
#pragma unroll
    for (int qn = 0; qn < SHW / 4; ++qn)
        *(uint4*)(orow + 4 * qn) =
            make_uint4(ow[4*qn], ow[4*qn+1], ow[4*qn+2], ow[4*qn+3]);
}

// ---------------------------------------------------------------------------
// MFMA dense: H' = ReLU(AGG @ Wrel^T + H @ Wroot^T + b).  13 m-tiles / 4 waves.
// ---------------------------------------------------------------------------
template <int CIN, int COUT, int KCA>
__device__ __forceinline__ void conv_dense(
    const _Float16* __restrict__ bufRoot,  // stride 24 halves
    const _Float16* __restrict__ bufAgg,
    _Float16* __restrict__ bufOut,
    const _Float16* __restrict__ wbrel, const _Float16* __restrict__ wbroot,
    const float* __restrict__ bias, int tid)
{
    const int lane = tid & 63, wid = tid >> 6;
    const int lrow = lane & 15, lgrp = lane >> 4;

    for (int mt = wid; mt < 13; mt += 4) {
        const int arow = mt * 16 + lrow;
        const _Float16* aA = bufAgg  + arow * 24 + lgrp * 4;
        const _Float16* aH = bufRoot + arow * 24 + lgrp * 4;
        const _Float16* bR = wbrel  + lrow * 16 + lgrp * 4;
        const _Float16* bT = wbroot + lrow * 16 + lgrp * 4;

        f32x4 acc = {0.f, 0.f, 0.f, 0.f};
#pragma unroll
        for (int kc = 0; kc < KCA; ++kc) {
            acc = __builtin_amdgcn_mfma_f32_16x16x16f16(
                *(const f16x4*)(aA + kc * 16),
                *(const f16x4*)(bR + kc * 256), acc, 0, 0, 0);
            acc = __builtin_amdgcn_mfma_f32_16x16x16f16(
                *(const f16x4*)(aH + kc * 16),
                *(const f16x4*)(bT + kc * 256), acc, 0, 0, 0);
        }
        if (lrow < COUT) {
            const float bv = bias[lrow];
#pragma unroll
            for (int j = 0; j < 4; ++j) {
                const int r = mt * 16 + lgrp * 4 + j;
                if (r < NPG)
                    bufOut[r * 24 + lrow] = (_Float16)fmaxf(acc[j] + bv, 0.f);
            }
        }
    }
}

__global__ __launch_bounds__(256) void conv_kernel(
    const float* __restrict__ x,
    const int*   __restrict__ eidx,
    const float* __restrict__ ew,
    const float* __restrict__ wr0, const float* __restrict__ br0,
    const float* __restrict__ wq0,
    const float* __restrict__ br1, const float* __restrict__ br2,
    const float* __restrict__ br3,
    const float* __restrict__ wr4, const float* __restrict__ br4,
    const float* __restrict__ wq4,
    const _Float16* __restrict__ cb,
    _Float16* __restrict__ H)            // row-major [NG][396] f16
{
    __shared__ __align__(16) unsigned s_edge[EPG];            // 6336 B
    __shared__ unsigned       cnt[256];
    __shared__ unsigned       cursor[256];
    __shared__ unsigned short row_start[NPG + 2];
    __shared__ unsigned       wsum[4];
    __shared__ unsigned       dhist[64];
    __shared__ unsigned       dcur[64];
    __shared__ unsigned short perm[NPG + 2];
    __shared__ __align__(16) unsigned bufA[NROW * SHW];       // 9984 B
    __shared__ __align__(16) unsigned bufB[NROW * SHW];       // 9984 B
    __shared__ __align__(16) unsigned bufG[NROW * SHW];       // 9984 B

    const int g = blockIdx.x, tid = threadIdx.x;
    const int ebase = g * EPG, nbase = g * NPG;
    const int lane = tid & 63, wid = tid >> 6;

    // --- zero feature buffers (pad rows / pad halves must be 0) -------------
    for (int i = tid; i < NROW * SHW; i += 256) {
        bufA[i] = 0u; bufB[i] = 0u; bufG[i] = 0u;
    }

    // --- load all edges once into registers ---------------------------------
    const int4*   s4 = (const int4*)(eidx + ebase);
    const int4*   d4 = (const int4*)(eidx + ETOT + ebase);
    const float4* w4 = (const float4*)(ew + ebase);
    const int4   sa = s4[tid];
    const int4   da = d4[tid];
    const float4 wa = w4[tid];
    const bool hasb = tid < (EPG / 4 - 256);
    int4 sb = {0,0,0,0}, db = {0,0,0,0}; float4 wb = {0,0,0,0};
    if (hasb) { sb = s4[tid + 256]; db = d4[tid + 256]; wb = w4[tid + 256]; }

    cnt[tid] = 0u;
    __syncthreads();
    atomicAdd(&cnt[da.x - nbase], 1u); atomicAdd(&cnt[da.y - nbase], 1u);
    atomicAdd(&cnt[da.z - nbase], 1u); atomicAdd(&cnt[da.w - nbase], 1u);
    if (hasb) {
        atomicAdd(&cnt[db.x - nbase], 1u); atomicAdd(&cnt[db.y - nbase], 1u);
        atomicAdd(&cnt[db.z - nbase], 1u); atomicAdd(&cnt[db.w - nbase], 1u);
    }
    __syncthreads();

    const unsigned v = cnt[tid];
    unsigned inc = v;
#pragma unroll
    for (int s = 1; s < 64; s <<= 1) {
        const unsigned t = (unsigned)__shfl_up((int)inc, s);
        if (lane >= s) inc += t;
    }
    if (lane == 63) wsum[wid] = inc;
    __syncthreads();
    unsigned pre = 0;
    for (int w = 0; w < wid; ++w) pre += wsum[w];
    const unsigned excl = pre + inc - v;
    if (tid <= NPG) row_start[tid] = (unsigned short)excl;
    if (tid < NPG)  cursor[tid]    = excl;
    __syncthreads();

    {
        auto place = [&](int s, int d, float w) {
            const int dl = d - nbase;
            const unsigned slot = atomicAdd(&cursor[dl], 1u);
            const __half hw = __float2half_rn(w);
            s_edge[slot] = ((unsigned)__half_as_ushort(hw) << 16)
                         | (unsigned)(s - nbase);
        };
        place(sa.x, da.x, wa.x); place(sa.y, da.y, wa.y);
        place(sa.z, da.z, wa.z); place(sa.w, da.w, wa.w);
        if (hasb) {
            place(sb.x, db.x, wb.x); place(sb.y, db.y, wb.y);
            place(sb.z, db.z, wb.z); place(sb.w, db.w, wb.w);
        }
    }

    // x lives at stride-1 words in bufA's first 198 words (zero elsewhere)
    if (tid < NPG) {
        const float2 xv = ((const float2*)x)[nbase + tid];
        bufA[tid] = __builtin_bit_cast(unsigned, __floats2half2_rn(xv.x, xv.y));
    }

    // --- degree-sorted permutation ------------------------------------------
    if (tid < 64) dhist[tid] = 0u;
    __syncthreads();
    unsigned mydeg = 0u;
    if (tid < NPG) {
        mydeg = v; if (mydeg > 63u) mydeg = 63u;
        atomicAdd(&dhist[mydeg], 1u);
    }
    __syncthreads();
    if (tid < 64) {
        const unsigned dv = dhist[tid];
        unsigned sc = dv;
#pragma unroll
        for (int s = 1; s < 64; s <<= 1) {
            const unsigned t = (unsigned)__shfl_up((int)sc, s);
            if (lane >= s) sc += t;
        }
        dcur[tid] = sc - dv;
    }
    __syncthreads();
    if (tid < NPG) {
        const unsigned pos = atomicAdd(&dcur[mydeg], 1u);
        perm[pos] = (unsigned short)tid;
    }
    __syncthreads();

    const _Float16* fA = (const _Float16*)bufA;
    const _Float16* fB = (const _Float16*)bufB;
    const _Float16* fG = (const _Float16*)bufG;

    // L0 (in-register, f32 weights): x(bufA,s1) -> bufB(s12)
    conv_layer_h<2, 20, 1, SHW>(bufA, bufB, s_edge, row_start, perm,
                                wr0, br0, wq0, tid);
    __syncthreads();

    // L1 (MFMA): bufB -> bufA
    gather_to_G<20>(bufB, bufG, s_edge, row_start, perm, tid);
    __syncthreads();
    conv_dense<20, 15, 2>(fB, fG, (_Float16*)bufA, cb + 1024, cb + 1536,
                          br1, tid);
    __syncthreads();

    // L2 (MFMA): bufA -> bufB
    gather_to_G<15>(bufA, bufG, s_edge, row_start, perm, tid);
    __syncthreads();
    conv_dense<15, 10, 1>(fA, fG, (_Float16*)bufB, cb + 2048, cb + 2304,
                          br2, tid);
    __syncthreads();

    // L3 (MFMA): bufB -> bufA
    gather_to_G<10>(bufB, bufG, s_edge, row_start, perm, tid);
    __syncthreads();
    conv_dense<10, 5, 1>(fB, fG, (_Float16*)bufA, cb + 2560, cb + 2816,
                         br3, tid);
    __syncthreads();

    // L4 (in-register, f32 weights): bufA(s12) -> bufB(s1)
    conv_layer_h<5, 2, SHW, 1>(bufA, bufB, s_edge, row_start, perm,
                               wr4, br4, wq4, tid);
    __syncthreads();

    if (tid < NPG)
        ((unsigned*)H)[g * 198 + tid] = bufB[tid];
}

// ---------------------------------------------------------------------------
// MLP as fused MFMA GEMM chain. 512 threads (8 waves = 2/SIMD); wave w owns
// N-tiles {w, w+8}. Fragment layouts as validated in round 7.
// ---------------------------------------------------------------------------
__device__ __forceinline__ void zero_words(void* p, int nwords, int tid)
{
    unsigned* u = (unsigned*)p;
    for (int i = tid; i < nwords; i += 512) u[i] = 0u;
}

template<int KC, int NTT, int NOUT, int SIN, int SOUT>
__device__ __forceinline__ void mfma_layer(
    const _Float16* __restrict__ inb,
    _Float16* __restrict__ outb,
    const _Float16* __restrict__ wtb,
    const float* __restrict__ bias, int tid)
{
    constexpr int NPAD = NTT * 16;
    const int lane = tid & 63, wid = tid >> 6;
    const int lrow = lane & 15, lgrp = lane >> 4;
    const int nt0 = wid;
    if (nt0 >= NTT) return;
    const bool has2 = (nt0 + 8) < NTT;
    const _Float16* aptr = inb + lrow * SIN + lgrp * 4;

    f32x4 acc0 = {0.f, 0.f, 0.f, 0.f};
    f32x4 acc1 = {0.f, 0.f, 0.f, 0.f};
    const int n0 = nt0 * 16 + lrow;
    const int n1 = (nt0 + 8) * 16 + lrow;
    const _Float16* b0 = wtb + n0 * 16 + lgrp * 4;
    const _Float16* b1 = wtb + n1 * 16 + lgrp * 4;
#pragma unroll 4
    for (int kc = 0; kc < KC; ++kc) {
        const f16x4 a = *(const f16x4*)(aptr + kc * 16);
        acc0 = __builtin_amdgcn_mfma_f32_16x16x16f16(
            a, *(const f16x4*)(b0 + (size_t)kc * (NPAD * 16)), acc0, 0, 0, 0);
        if (has2)
            acc1 = __builtin_amdgcn_mfma_f32_16x16x16f16(
                a, *(const f16x4*)(b1 + (size_t)kc * (NPAD * 16)), acc1, 0, 0, 0);
    }
    if (n0 < NOUT) {
        const float bv = bias[n0];
#pragma unroll
        for (int j = 0; j < 4; ++j)
            outb[(lgrp * 4 + j) * SOUT + n0] = (_Float16)fmaxf(acc0[j] + bv, 0.f);
    }
    if (has2 && n1 < NOUT) {
        const float bv = bias[n1];
#pragma unroll
        for (int j = 0; j < 4; ++j)
            outb[(lgrp * 4 + j) * SOUT + n1] = (_Float16)fmaxf(acc1[j] + bv, 0.f);
    }
}

__global__ __launch_bounds__(512) void mlp_mfma_kernel(
    const _Float16* __restrict__ H,
    const _Float16* __restrict__ wtb,
    const float* __restrict__ lb0, const float* __restrict__ lb1,
    const float* __restrict__ lb2, const float* __restrict__ lb3,
    const float* __restrict__ lw4, const float* __restrict__ lb4,
    float* __restrict__ out)
{
    __shared__ __align__(16) _Float16 bufH[16 * 400];
    __shared__ __align__(16) _Float16 bufX[16 * 224];
    __shared__ __align__(16) _Float16 bufY[16 * 128];

    const int tid   = threadIdx.x;
    const int gbase = blockIdx.x * 16;

    {
        const unsigned* Hw = (const unsigned*)H + (size_t)gbase * 198;
        unsigned* bH = (unsigned*)bufH;
        for (int t = tid; t < 16 * 200; t += 512) {
            const int gg = t / 200, w = t - gg * 200;
            bH[gg * 200 + w] = (w < 198) ? Hw[gg * 198 + w] : 0u;
        }
        zero_words(bufX, 16 * 224 / 2, tid);
        zero_words(bufY, 16 * 128 / 2, tid);
    }
    __syncthreads();

    mfma_layer<25, 13, 200, 400, 224>(bufH, bufX, wtb, lb0, tid);
    __syncthreads();

    zero_words(bufH, 512, tid);
    mfma_layer<13, 7, 100, 224, 128>(bufX, bufY, wtb + WTB1_OFF, lb1, tid);
    __syncthreads();

    zero_words(bufX, 128, tid);
    mfma_layer<7, 4, 50, 128, 64>(bufY, bufH, wtb + WTB2_OFF, lb2, tid);
    __syncthreads();

    mfma_layer<4, 1, 10, 64, 16>(bufH, bufX, wtb + WTB3_OFF, lb3, tid);
    __syncthreads();

    if (tid < 16) {
        float l0 = lb4[0], l1 = lb4[1];
#pragma unroll
        for (int k = 0; k < 10; ++k) {
            const float hv = (float)bufX[tid * 16 + k];
            l0 = fmaf(hv, lw4[k],      l0);
            l1 = fmaf(hv, lw4[10 + k], l1);
        }
        const float m  = fmaxf(l0, l1);
        const float e0 = __expf(l0 - m), e1 = __expf(l1 - m);
        const float inv = 1.f / (e0 + e1);
        float2 p; p.x = e0 * inv; p.y = e1 * inv;
        ((float2*)out)[gbase + tid] = p;
    }
}

extern "C" void kernel_launch(void* const* d_in, const int* in_sizes, int n_in,
                              void* d_out, int out_size, void* d_ws, size_t ws_size,
                              hipStream_t stream)
{
    const float* x    = (const float*)d_in[0];
    const int*   eidx = (const int*)  d_in[1];
    const float* ew   = (const float*)d_in[2];

    const float* wr[5]; const float* br[5]; const float* wq[5];
    for (int i = 0; i < 5; ++i) {
        wr[i] = (const float*)d_in[3 + 3 * i];
        br[i] = (const float*)d_in[4 + 3 * i];
        wq[i] = (const float*)d_in[5 + 3 * i];
    }
    const float* lw[5]; const float* lb[5];
    for (int i = 0; i < 5; ++i) {
        lw[i] = (const float*)d_in[18 + 2 * i];
        lb[i] = (const float*)d_in[19 + 2 * i];
    }

    _Float16* wsH = (_Float16*)d_ws;                  // H: [NG][396] f16
    _Float16* wtb = wsH + (size_t)H_F16S;             // packed MLP weights
    _Float16* cb  = wtb + (size_t)WTB_TOTAL;          // packed conv weights

    wtrans16_kernel<<<(WTB_TOTAL + 255) / 256, 256, 0, stream>>>(
        lw[0], lw[1], lw[2], lw[3], wtb);

    wconv16_kernel<<<(CB_TOTAL + 255) / 256, 256, 0, stream>>>(
        wr[0], wq[0], wr[1], wq[1], wr[2], wq[2], wr[3], wq[3], wr[4], wq[4],
        cb);

    conv_kernel<<<NG, 256, 0, stream>>>(
        x, eidx, ew,
        wr[0], br[0], wq[0],
        br[1], br[2], br[3],
        wr[4], br[4], wq[4],
        cb, wsH);

    mlp_mfma_kernel<<<NG / 16, 512, 0, stream>>>(
        wsH, wtb,
        lb[0], lb[1], lb[2], lb[3],
        lw[4], lb[4],
        (float*)d_out);
}